// Round 1
// baseline (211.837 us; speedup 1.0000x reference)
//
#include <hip/hip_runtime.h>
#include <hip/hip_bf16.h>
#include <math.h>

typedef __attribute__((ext_vector_type(8))) short bf16x8;
typedef __attribute__((ext_vector_type(4))) float f32x4;

#define MFMA16(a,b,c) __builtin_amdgcn_mfma_f32_16x16x32_bf16((a),(b),(c),0,0,0)

__device__ __forceinline__ unsigned short f2bf_u(float x){
  union { float f; unsigned int u; } v; v.f = x;
  unsigned int r = v.u + 0x7fffu + ((v.u >> 16) & 1u);
  return (unsigned short)(r >> 16);
}
__device__ __forceinline__ unsigned int pack2(float a, float b){
  return (unsigned int)f2bf_u(a) | ((unsigned int)f2bf_u(b) << 16);
}
__device__ __forceinline__ float gelu_tanh_f(float x){
  float y = 0.7978845608028654f * (x + 0.044715f * x * x * x);
  float e = __expf(2.0f * y);
  float t = 1.0f - 2.0f / (e + 1.0f);
  return 0.5f * x * (1.0f + t);
}
__device__ __forceinline__ float gelu_erf_f(float x){
  return 0.5f * x * (1.0f + erff(x * 0.70710678118654752f));
}

// ---------------- prep: weights -> bf16, [out][in] layout ----------------
// wt layout (elements): W1T[128][256] @0, W2T[128][128] @32768, W3T[128][128] @49152,
//                       WinT[512][128] @65536, WoutT[128][512] @131072  (total 196608)
__global__ void k_prep(const float* __restrict__ W1, const float* __restrict__ W2,
                       const float* __restrict__ W3, const float* __restrict__ Win,
                       const float* __restrict__ Wout, unsigned short* __restrict__ wt)
{
  int t = blockIdx.x * 256 + threadIdx.x;
  if (t >= 196608) return;
  float v;
  if (t < 32768){            int o = t >> 8,        i = t & 255;         v = W1[i*128 + o]; }
  else if (t < 49152){       int l = t - 32768, o = l >> 7, i = l & 127; v = W2[i*128 + o]; }
  else if (t < 65536){       int l = t - 49152, o = l >> 7, i = l & 127; v = W3[i*128 + o]; }
  else if (t < 131072){      int l = t - 65536, o = l >> 7, i = l & 127; v = Win[i*512 + o]; }
  else {                     int l = t - 131072, o = l >> 9, i = l & 511; v = Wout[i*128 + o]; }
  wt[t] = f2bf_u(v);
}

// ---------------- message MLP + aggregation ----------------
__global__ __launch_bounds__(256, 2)
void k_msg(const float* __restrict__ hV, const float* __restrict__ hE,
           const int* __restrict__ Eidx, const float* __restrict__ maskA,
           const unsigned short* __restrict__ wt,
           const float* __restrict__ b1, const float* __restrict__ b2,
           const float* __restrict__ b3, float* __restrict__ hOut)
{
  __shared__ char  sEV[96*512];   // 96 rows x 256 bf16 (swizzled)
  __shared__ char  sM [96*256];   // 96 rows x 128 bf16 (swizzled)
  __shared__ int   sIdx[96];
  __shared__ float sMask[96];

  const int tid = threadIdx.x;
  const int wv  = tid >> 6;
  const int ln  = tid & 63;
  const int l15 = ln & 15;
  const int l4  = ln >> 4;
  const int swz = (l15 & 7) << 4;

  const unsigned short* W1T = wt;            // [128][256]
  const unsigned short* W2T = wt + 32768;    // [128][128]
  const unsigned short* W3T = wt + 49152;    // [128][128]

  // register-resident weight fragments (loop-invariant)
  bf16x8 w1f[2][8], w2f[2][4], w3f[2][4];
#pragma unroll
  for (int m = 0; m < 2; ++m){
    int orow = (wv*2 + m)*16 + l15;
#pragma unroll
    for (int ks = 0; ks < 8; ++ks)
      w1f[m][ks] = *(const bf16x8*)(W1T + orow*256 + ks*32 + l4*8);
#pragma unroll
    for (int ks = 0; ks < 4; ++ks){
      w2f[m][ks] = *(const bf16x8*)(W2T + orow*128 + ks*32 + l4*8);
      w3f[m][ks] = *(const bf16x8*)(W3T + orow*128 + ks*32 + l4*8);
    }
  }

  for (int pair = blockIdx.x; pair < 4096; pair += gridDim.x){
    const int b  = pair >> 10;
    const int n0 = (pair & 1023) << 1;

    if (tid < 96){
      int half = (tid >= 48);
      int node = n0 + half;
      int k = tid - 48*half;
      int e = (b*2048 + node)*48 + k;
      sIdx[tid]  = Eidx[e];
      sMask[tid] = maskA[e];
    }
    __syncthreads();

    // stage h_EV: cols 0..127 = gathered h_V, cols 128..255 = h_E
#pragma unroll
    for (int it = 0; it < 6; ++it){
      int cid = tid + it*256;            // 0..1535 (96 rows x 16 chunks of 8 cols)
      int r = cid >> 4, cb = cid & 15;
      int half = (r >= 48);
      int node = n0 + half;
      int k = r - 48*half;
      const float* eptr = hE + (size_t)((b*2048 + node)*48 + k)*128 + cb*8;
      float4 e0 = *(const float4*)(eptr);
      float4 e1 = *(const float4*)(eptr + 4);
      uint4 w;
      w.x = pack2(e0.x, e0.y); w.y = pack2(e0.z, e0.w);
      w.z = pack2(e1.x, e1.y); w.w = pack2(e1.z, e1.w);
      *(uint4*)(&sEV[r*512 + ((256 + cb*16) ^ ((r&7)<<4))]) = w;

      const float* vptr = hV + (size_t)(b*2048 + sIdx[r])*128 + cb*8;
      float4 v0 = *(const float4*)(vptr);
      float4 v1 = *(const float4*)(vptr + 4);
      uint4 u;
      u.x = pack2(v0.x, v0.y); u.y = pack2(v0.z, v0.w);
      u.z = pack2(v1.x, v1.y); u.w = pack2(v1.z, v1.w);
      *(uint4*)(&sEV[r*512 + ((cb*16) ^ ((r&7)<<4))]) = u;
    }
    __syncthreads();

    f32x4 acc[2][6];

    // ---- GEMM1: m1^T[128][96], K=256
#pragma unroll
    for (int m = 0; m < 2; ++m)
#pragma unroll
      for (int nt = 0; nt < 6; ++nt) acc[m][nt] = f32x4{0.f,0.f,0.f,0.f};
#pragma unroll
    for (int ks = 0; ks < 8; ++ks){
#pragma unroll
      for (int nt = 0; nt < 6; ++nt){
        bf16x8 x = *(const bf16x8*)(&sEV[(nt*16 + l15)*512 + ((ks*64 + l4*16) ^ swz)]);
        acc[0][nt] = MFMA16(w1f[0][ks], x, acc[0][nt]);
        acc[1][nt] = MFMA16(w1f[1][ks], x, acc[1][nt]);
      }
    }
    // epilogue 1: bias + gelu(tanh) -> sM (bf16)
#pragma unroll
    for (int m = 0; m < 2; ++m){
      int och0 = (wv*2 + m)*16 + l4*4;
      float q0 = b1[och0], q1 = b1[och0+1], q2 = b1[och0+2], q3 = b1[och0+3];
#pragma unroll
      for (int nt = 0; nt < 6; ++nt){
        int row = nt*16 + l15;
        float g0 = gelu_tanh_f(acc[m][nt][0] + q0);
        float g1 = gelu_tanh_f(acc[m][nt][1] + q1);
        float g2 = gelu_tanh_f(acc[m][nt][2] + q2);
        float g3 = gelu_tanh_f(acc[m][nt][3] + q3);
        uint2 p; p.x = pack2(g0, g1); p.y = pack2(g2, g3);
        *(uint2*)(&sM[row*256 + ((och0*2) ^ swz)]) = p;
      }
    }
    __syncthreads();

    // ---- GEMM2: K=128
#pragma unroll
    for (int m = 0; m < 2; ++m)
#pragma unroll
      for (int nt = 0; nt < 6; ++nt) acc[m][nt] = f32x4{0.f,0.f,0.f,0.f};
#pragma unroll
    for (int ks = 0; ks < 4; ++ks){
#pragma unroll
      for (int nt = 0; nt < 6; ++nt){
        bf16x8 x = *(const bf16x8*)(&sM[(nt*16 + l15)*256 + ((ks*64 + l4*16) ^ swz)]);
        acc[0][nt] = MFMA16(w2f[0][ks], x, acc[0][nt]);
        acc[1][nt] = MFMA16(w2f[1][ks], x, acc[1][nt]);
      }
    }
    __syncthreads();   // all sM reads done before overwrite
    // epilogue 2
#pragma unroll
    for (int m = 0; m < 2; ++m){
      int och0 = (wv*2 + m)*16 + l4*4;
      float q0 = b2[och0], q1 = b2[och0+1], q2 = b2[och0+2], q3 = b2[och0+3];
#pragma unroll
      for (int nt = 0; nt < 6; ++nt){
        int row = nt*16 + l15;
        float g0 = gelu_tanh_f(acc[m][nt][0] + q0);
        float g1 = gelu_tanh_f(acc[m][nt][1] + q1);
        float g2 = gelu_tanh_f(acc[m][nt][2] + q2);
        float g3 = gelu_tanh_f(acc[m][nt][3] + q3);
        uint2 p; p.x = pack2(g0, g1); p.y = pack2(g2, g3);
        *(uint2*)(&sM[row*256 + ((och0*2) ^ swz)]) = p;
      }
    }
    __syncthreads();

    // ---- GEMM3: K=128
#pragma unroll
    for (int m = 0; m < 2; ++m)
#pragma unroll
      for (int nt = 0; nt < 6; ++nt) acc[m][nt] = f32x4{0.f,0.f,0.f,0.f};
#pragma unroll
    for (int ks = 0; ks < 4; ++ks){
#pragma unroll
      for (int nt = 0; nt < 6; ++nt){
        bf16x8 x = *(const bf16x8*)(&sM[(nt*16 + l15)*256 + ((ks*64 + l4*16) ^ swz)]);
        acc[0][nt] = MFMA16(w3f[0][ks], x, acc[0][nt]);
        acc[1][nt] = MFMA16(w3f[1][ks], x, acc[1][nt]);
      }
    }
    // epilogue 3: +b3, mask, sum over 48 edges, /30, +h_V -> hOut (fp32)
#pragma unroll
    for (int m = 0; m < 2; ++m){
      int och0 = (wv*2 + m)*16 + l4*4;
      float q0 = b3[och0], q1 = b3[och0+1], q2 = b3[och0+2], q3 = b3[och0+3];
#pragma unroll
      for (int half = 0; half < 2; ++half){
        float s0 = 0.f, s1 = 0.f, s2 = 0.f, s3 = 0.f;
#pragma unroll
        for (int q = 0; q < 3; ++q){
          int nt = half*3 + q;
          float mk = sMask[nt*16 + l15];
          s0 += mk * (acc[m][nt][0] + q0);
          s1 += mk * (acc[m][nt][1] + q1);
          s2 += mk * (acc[m][nt][2] + q2);
          s3 += mk * (acc[m][nt][3] + q3);
        }
#pragma unroll
        for (int off = 1; off < 16; off <<= 1){
          s0 += __shfl_xor(s0, off, 16);
          s1 += __shfl_xor(s1, off, 16);
          s2 += __shfl_xor(s2, off, 16);
          s3 += __shfl_xor(s3, off, 16);
        }
        if (l15 == 0){
          int node = b*2048 + n0 + half;
          const float4 hv = *(const float4*)(hV + (size_t)node*128 + och0);
          float4 o;
          o.x = hv.x + s0 * (1.0f/30.0f);
          o.y = hv.y + s1 * (1.0f/30.0f);
          o.z = hv.z + s2 * (1.0f/30.0f);
          o.w = hv.w + s3 * (1.0f/30.0f);
          *(float4*)(hOut + (size_t)node*128 + och0) = o;
        }
      }
    }
    __syncthreads();   // protect sIdx/sMask/sEV against next iteration's staging
  }
}

// ---------------- FFN ----------------
__global__ __launch_bounds__(256, 2)
void k_ffn(const float* __restrict__ h, const float* __restrict__ maskV,
           const unsigned short* __restrict__ wt,
           const float* __restrict__ bin, const float* __restrict__ bout,
           float* __restrict__ out)
{
  __shared__ char sH[32*256];    // 32 nodes x 128 bf16 (swizzled)
  __shared__ char sF[32*1024];   // 32 nodes x 512 bf16 (swizzled)

  const int tid = threadIdx.x;
  const int wv  = tid >> 6;
  const int ln  = tid & 63;
  const int l15 = ln & 15;
  const int l4  = ln >> 4;
  const int swz = (l15 & 7) << 4;
  const unsigned short* WinT  = wt + 65536;    // [512][128]
  const unsigned short* WoutT = wt + 131072;   // [128][512]
  const int nb = blockIdx.x * 32;              // flat node base

#pragma unroll
  for (int it = 0; it < 2; ++it){
    int cid = tid + it*256;          // 512 chunks: 32 rows x 16 chunks
    int r = cid >> 4, cb = cid & 15;
    const float* src = h + (size_t)(nb + r)*128 + cb*8;
    float4 a0 = *(const float4*)(src);
    float4 a1 = *(const float4*)(src + 4);
    uint4 w;
    w.x = pack2(a0.x, a0.y); w.y = pack2(a0.z, a0.w);
    w.z = pack2(a1.x, a1.y); w.w = pack2(a1.z, a1.w);
    *(uint4*)(&sH[r*256 + ((cb*16) ^ ((r&7)<<4))]) = w;
  }
  __syncthreads();

  // GEMM in: ff^T[512][32], K=128 — wave owns 8 f-tiles
  f32x4 accA[8][2];
#pragma unroll
  for (int m8 = 0; m8 < 8; ++m8){ accA[m8][0] = f32x4{0.f,0.f,0.f,0.f}; accA[m8][1] = f32x4{0.f,0.f,0.f,0.f}; }
#pragma unroll
  for (int ks = 0; ks < 4; ++ks){
    bf16x8 x0 = *(const bf16x8*)(&sH[(l15)*256      + ((ks*64 + l4*16) ^ swz)]);
    bf16x8 x1 = *(const bf16x8*)(&sH[(16 + l15)*256 + ((ks*64 + l4*16) ^ swz)]);
#pragma unroll
    for (int m8 = 0; m8 < 8; ++m8){
      int fr = (wv*8 + m8)*16 + l15;
      bf16x8 wf = *(const bf16x8*)(WinT + fr*128 + ks*32 + l4*8);
      accA[m8][0] = MFMA16(wf, x0, accA[m8][0]);
      accA[m8][1] = MFMA16(wf, x1, accA[m8][1]);
    }
  }
#pragma unroll
  for (int m8 = 0; m8 < 8; ++m8){
    int f0 = (wv*8 + m8)*16 + l4*4;
    float q0 = bin[f0], q1 = bin[f0+1], q2 = bin[f0+2], q3 = bin[f0+3];
#pragma unroll
    for (int nt = 0; nt < 2; ++nt){
      int row = nt*16 + l15;
      float g0 = gelu_erf_f(accA[m8][nt][0] + q0);
      float g1 = gelu_erf_f(accA[m8][nt][1] + q1);
      float g2 = gelu_erf_f(accA[m8][nt][2] + q2);
      float g3 = gelu_erf_f(accA[m8][nt][3] + q3);
      uint2 p; p.x = pack2(g0, g1); p.y = pack2(g2, g3);
      *(uint2*)(&sF[row*1024 + ((f0*2) ^ swz)]) = p;
    }
  }
  __syncthreads();

  // GEMM out: dh2^T[128][32], K=512 — wave owns 2 ch-tiles
  f32x4 accB[2][2];
#pragma unroll
  for (int m = 0; m < 2; ++m){ accB[m][0] = f32x4{0.f,0.f,0.f,0.f}; accB[m][1] = f32x4{0.f,0.f,0.f,0.f}; }
#pragma unroll
  for (int ks = 0; ks < 16; ++ks){
    bf16x8 x0 = *(const bf16x8*)(&sF[(l15)*1024      + ((ks*64 + l4*16) ^ swz)]);
    bf16x8 x1 = *(const bf16x8*)(&sF[(16 + l15)*1024 + ((ks*64 + l4*16) ^ swz)]);
#pragma unroll
    for (int m = 0; m < 2; ++m){
      int cr = (wv*2 + m)*16 + l15;
      bf16x8 wf = *(const bf16x8*)(WoutT + cr*512 + ks*32 + l4*8);
      accB[m][0] = MFMA16(wf, x0, accB[m][0]);
      accB[m][1] = MFMA16(wf, x1, accB[m][1]);
    }
  }
#pragma unroll
  for (int m = 0; m < 2; ++m){
    int ch0 = (wv*2 + m)*16 + l4*4;
    float q0 = bout[ch0], q1 = bout[ch0+1], q2 = bout[ch0+2], q3 = bout[ch0+3];
#pragma unroll
    for (int nt = 0; nt < 2; ++nt){
      int node = nb + nt*16 + l15;
      float mv = maskV[node];
      const float4 hv = *(const float4*)(h + (size_t)node*128 + ch0);
      float4 o;
      o.x = mv * (hv.x + accB[m][nt][0] + q0);
      o.y = mv * (hv.y + accB[m][nt][1] + q1);
      o.z = mv * (hv.z + accB[m][nt][2] + q2);
      o.w = mv * (hv.w + accB[m][nt][3] + q3);
      *(float4*)(out + (size_t)node*128 + ch0) = o;
    }
  }
}

extern "C" void kernel_launch(void* const* d_in, const int* in_sizes, int n_in,
                              void* d_out, int out_size, void* d_ws, size_t ws_size,
                              hipStream_t stream)
{
  const float* hV    = (const float*)d_in[0];
  const float* hE    = (const float*)d_in[1];
  const int*   Eidx  = (const int*)  d_in[2];
  const float* maskV = (const float*)d_in[3];
  const float* maskA = (const float*)d_in[4];
  const float* W1w = (const float*)d_in[5];
  const float* W1b = (const float*)d_in[6];
  const float* W2w = (const float*)d_in[7];
  const float* W2b = (const float*)d_in[8];
  const float* W3w = (const float*)d_in[9];
  const float* W3b = (const float*)d_in[10];
  const float* Winw  = (const float*)d_in[11];
  const float* Winb  = (const float*)d_in[12];
  const float* Woutw = (const float*)d_in[13];
  const float* Woutb = (const float*)d_in[14];
  float* out = (float*)d_out;

  float* hbuf = (float*)d_ws;                                   // 4 MB fp32 h
  unsigned short* wt = (unsigned short*)((char*)d_ws + (4u << 20));  // bf16 weights

  k_prep<<<dim3(768), dim3(256), 0, stream>>>(W1w, W2w, W3w, Winw, Woutw, wt);
  k_msg <<<dim3(512), dim3(256), 0, stream>>>(hV, hE, Eidx, maskA, wt, W1b, W2b, W3b, hbuf);
  k_ffn <<<dim3(256), dim3(256), 0, stream>>>(hbuf, maskV, wt, Winb, Woutb, out);
}

// Round 2
// 170.035 us; speedup vs baseline: 1.2458x; 1.2458x over previous
//
#include <hip/hip_runtime.h>
#include <hip/hip_bf16.h>
#include <math.h>

typedef __attribute__((ext_vector_type(8))) short bf16x8;
typedef __attribute__((ext_vector_type(4))) float f32x4;

#define MFMA16(a,b,c) __builtin_amdgcn_mfma_f32_16x16x32_bf16((a),(b),(c),0,0,0)

__device__ __forceinline__ unsigned int pack2(float a, float b){
  __hip_bfloat162 h = __float22bfloat162_rn(float2{a, b});
  union { __hip_bfloat162 h; unsigned int u; } v; v.h = h;
  return v.u;
}
__device__ __forceinline__ float gelu_tanh_f(float x){
  float y = 0.7978845608028654f * (x + 0.044715f * x * x * x);
  float e = __expf(2.0f * y);
  float t = 1.0f - 2.0f / (e + 1.0f);
  return 0.5f * x * (1.0f + t);
}
__device__ __forceinline__ float gelu_erf_f(float x){
  return 0.5f * x * (1.0f + erff(x * 0.70710678118654752f));
}

// ---------------- prep: weights -> bf16, [out][in] layout ----------------
// wt layout (elements): W1T[128][256] @0, W2T[128][128] @32768, W3T[128][128] @49152,
//                       WinT[512][128] @65536, WoutT[128][512] @131072  (total 196608)
__global__ void k_prep(const float* __restrict__ W1, const float* __restrict__ W2,
                       const float* __restrict__ W3, const float* __restrict__ Win,
                       const float* __restrict__ Wout, unsigned short* __restrict__ wt)
{
  int t = blockIdx.x * 256 + threadIdx.x;
  if (t >= 196608) return;
  float v;
  if (t < 32768){            int o = t >> 8,        i = t & 255;         v = W1[i*128 + o]; }
  else if (t < 49152){       int l = t - 32768, o = l >> 7, i = l & 127; v = W2[i*128 + o]; }
  else if (t < 65536){       int l = t - 49152, o = l >> 7, i = l & 127; v = W3[i*128 + o]; }
  else if (t < 131072){      int l = t - 65536, o = l >> 7, i = l & 127; v = Win[i*512 + o]; }
  else {                     int l = t - 131072, o = l >> 9, i = l & 511; v = Wout[i*128 + o]; }
  union { float f; unsigned int u; } w; w.f = v;
  unsigned int r = w.u + 0x7fffu + ((w.u >> 16) & 1u);
  wt[t] = (unsigned short)(r >> 16);
}

// ---------------- hVp = hV @ W1a^T + b1  (per node, fp32 out) ----------------
__global__ __launch_bounds__(256)
void k_hvp(const float* __restrict__ hV, const unsigned short* __restrict__ wt,
           const float* __restrict__ b1, float* __restrict__ hVp)
{
  __shared__ char sH[32*256];   // 32 nodes x 128 bf16 (swizzled)
  const int tid = threadIdx.x;
  const int wv  = tid >> 6;
  const int ln  = tid & 63;
  const int l15 = ln & 15;
  const int l4  = ln >> 4;
  const int swz = (l15 & 7) << 4;
  const unsigned short* W1T = wt;   // [128][256], cols 0..127 = h_V part
  const int nb = blockIdx.x * 32;

#pragma unroll
  for (int it = 0; it < 2; ++it){
    int cid = tid + it*256;       // 32 rows x 16 chunks
    int r = cid >> 4, cb = cid & 15;
    const float* src = hV + (size_t)(nb + r)*128 + cb*8;
    float4 a0 = *(const float4*)(src);
    float4 a1 = *(const float4*)(src + 4);
    uint4 w;
    w.x = pack2(a0.x, a0.y); w.y = pack2(a0.z, a0.w);
    w.z = pack2(a1.x, a1.y); w.w = pack2(a1.z, a1.w);
    *(uint4*)(&sH[r*256 + ((cb*16) ^ ((r&7)<<4))]) = w;
  }
  __syncthreads();

  f32x4 acc[2][2];
#pragma unroll
  for (int m = 0; m < 2; ++m){ acc[m][0] = f32x4{0.f,0.f,0.f,0.f}; acc[m][1] = f32x4{0.f,0.f,0.f,0.f}; }
#pragma unroll
  for (int ks = 0; ks < 4; ++ks){
    bf16x8 x0 = *(const bf16x8*)(&sH[(l15)*256      + ((ks*64 + l4*16) ^ swz)]);
    bf16x8 x1 = *(const bf16x8*)(&sH[(16 + l15)*256 + ((ks*64 + l4*16) ^ swz)]);
#pragma unroll
    for (int m = 0; m < 2; ++m){
      int orow = (wv*2 + m)*16 + l15;
      bf16x8 wf = *(const bf16x8*)(W1T + orow*256 + ks*32 + l4*8);
      acc[m][0] = MFMA16(wf, x0, acc[m][0]);
      acc[m][1] = MFMA16(wf, x1, acc[m][1]);
    }
  }
#pragma unroll
  for (int m = 0; m < 2; ++m){
    int och0 = (wv*2 + m)*16 + l4*4;
    float q0 = b1[och0], q1 = b1[och0+1], q2 = b1[och0+2], q3 = b1[och0+3];
#pragma unroll
    for (int nt = 0; nt < 2; ++nt){
      int node = nb + nt*16 + l15;
      float4 o;
      o.x = acc[m][nt][0] + q0;
      o.y = acc[m][nt][1] + q1;
      o.z = acc[m][nt][2] + q2;
      o.w = acc[m][nt][3] + q3;
      *(float4*)(hVp + (size_t)node*128 + och0) = o;
    }
  }
}

// ---------------- message MLP + aggregation (one node per block) ----------------
__global__ __launch_bounds__(256, 4)
void k_msg(const float* __restrict__ hV, const float* __restrict__ hE,
           const int* __restrict__ Eidx, const float* __restrict__ maskA,
           const unsigned short* __restrict__ wt, const float* __restrict__ hVp,
           const float* __restrict__ b2, const float* __restrict__ b3,
           float* __restrict__ hOut)
{
  __shared__ char  sA[48*256];   // 48 rows x 128 bf16 (swizzled): h_E, later m2
  __shared__ char  sB[48*256];   // m1
  __shared__ int   sIdx[48];
  __shared__ float sMask[48];

  const int tid = threadIdx.x;
  const int wv  = tid >> 6;
  const int ln  = tid & 63;
  const int l15 = ln & 15;
  const int l4  = ln >> 4;
  const int swz = (l15 & 7) << 4;

  const unsigned short* W1T = wt;            // [128][256]; h_E part at col 128
  const unsigned short* W2T = wt + 32768;    // [128][128]
  const unsigned short* W3T = wt + 49152;    // [128][128]

  const int node = blockIdx.x;               // flat b*2048+n
  const int b    = node >> 11;

  if (tid < 48){
    int e = node*48 + tid;
    sIdx[tid]  = Eidx[e];
    sMask[tid] = maskA[e];
  }

  // stage h_E tile: 48 rows x 16 chunks of 8 cols
#pragma unroll
  for (int it = 0; it < 3; ++it){
    int cid = tid + it*256;
    int r = cid >> 4, cb = cid & 15;
    const float* eptr = hE + (size_t)(node*48 + r)*128 + cb*8;
    float4 e0 = *(const float4*)(eptr);
    float4 e1 = *(const float4*)(eptr + 4);
    uint4 w;
    w.x = pack2(e0.x, e0.y); w.y = pack2(e0.z, e0.w);
    w.z = pack2(e1.x, e1.y); w.w = pack2(e1.z, e1.w);
    *(uint4*)(&sA[r*256 + ((cb*16) ^ ((r&7)<<4))]) = w;
  }
  __syncthreads();

  f32x4 acc[2][3];

  // ---- GEMM1: K=128 (h_E part of W1)
#pragma unroll
  for (int m = 0; m < 2; ++m)
#pragma unroll
    for (int nt = 0; nt < 3; ++nt) acc[m][nt] = f32x4{0.f,0.f,0.f,0.f};
#pragma unroll
  for (int ks = 0; ks < 4; ++ks){
    bf16x8 w0 = *(const bf16x8*)(W1T + ((wv*2+0)*16 + l15)*256 + 128 + ks*32 + l4*8);
    bf16x8 w1 = *(const bf16x8*)(W1T + ((wv*2+1)*16 + l15)*256 + 128 + ks*32 + l4*8);
#pragma unroll
    for (int nt = 0; nt < 3; ++nt){
      bf16x8 x = *(const bf16x8*)(&sA[(nt*16 + l15)*256 + ((ks*64 + l4*16) ^ swz)]);
      acc[0][nt] = MFMA16(w0, x, acc[0][nt]);
      acc[1][nt] = MFMA16(w1, x, acc[1][nt]);
    }
  }
  // epilogue 1: + gathered hVp (contains b1), gelu(tanh) -> sB
#pragma unroll
  for (int m = 0; m < 2; ++m){
    int och0 = (wv*2 + m)*16 + l4*4;
#pragma unroll
    for (int nt = 0; nt < 3; ++nt){
      int row = nt*16 + l15;
      const float4 hp = *(const float4*)(hVp + (size_t)(b*2048 + sIdx[row])*128 + och0);
      float g0 = gelu_tanh_f(acc[m][nt][0] + hp.x);
      float g1 = gelu_tanh_f(acc[m][nt][1] + hp.y);
      float g2 = gelu_tanh_f(acc[m][nt][2] + hp.z);
      float g3 = gelu_tanh_f(acc[m][nt][3] + hp.w);
      uint2 p; p.x = pack2(g0, g1); p.y = pack2(g2, g3);
      *(uint2*)(&sB[row*256 + ((och0*2) ^ ((row&7)<<4))]) = p;
    }
  }
  __syncthreads();

  // ---- GEMM2: K=128
#pragma unroll
  for (int m = 0; m < 2; ++m)
#pragma unroll
    for (int nt = 0; nt < 3; ++nt) acc[m][nt] = f32x4{0.f,0.f,0.f,0.f};
#pragma unroll
  for (int ks = 0; ks < 4; ++ks){
    bf16x8 w0 = *(const bf16x8*)(W2T + ((wv*2+0)*16 + l15)*128 + ks*32 + l4*8);
    bf16x8 w1 = *(const bf16x8*)(W2T + ((wv*2+1)*16 + l15)*128 + ks*32 + l4*8);
#pragma unroll
    for (int nt = 0; nt < 3; ++nt){
      bf16x8 x = *(const bf16x8*)(&sB[(nt*16 + l15)*256 + ((ks*64 + l4*16) ^ swz)]);
      acc[0][nt] = MFMA16(w0, x, acc[0][nt]);
      acc[1][nt] = MFMA16(w1, x, acc[1][nt]);
    }
  }
  // epilogue 2: bias + gelu -> sA (h_E tile no longer needed)
#pragma unroll
  for (int m = 0; m < 2; ++m){
    int och0 = (wv*2 + m)*16 + l4*4;
    float q0 = b2[och0], q1 = b2[och0+1], q2 = b2[och0+2], q3 = b2[och0+3];
#pragma unroll
    for (int nt = 0; nt < 3; ++nt){
      int row = nt*16 + l15;
      float g0 = gelu_tanh_f(acc[m][nt][0] + q0);
      float g1 = gelu_tanh_f(acc[m][nt][1] + q1);
      float g2 = gelu_tanh_f(acc[m][nt][2] + q2);
      float g3 = gelu_tanh_f(acc[m][nt][3] + q3);
      uint2 p; p.x = pack2(g0, g1); p.y = pack2(g2, g3);
      *(uint2*)(&sA[row*256 + ((och0*2) ^ ((row&7)<<4))]) = p;
    }
  }
  __syncthreads();

  // ---- GEMM3: K=128
#pragma unroll
  for (int m = 0; m < 2; ++m)
#pragma unroll
    for (int nt = 0; nt < 3; ++nt) acc[m][nt] = f32x4{0.f,0.f,0.f,0.f};
#pragma unroll
  for (int ks = 0; ks < 4; ++ks){
    bf16x8 w0 = *(const bf16x8*)(W3T + ((wv*2+0)*16 + l15)*128 + ks*32 + l4*8);
    bf16x8 w1 = *(const bf16x8*)(W3T + ((wv*2+1)*16 + l15)*128 + ks*32 + l4*8);
#pragma unroll
    for (int nt = 0; nt < 3; ++nt){
      bf16x8 x = *(const bf16x8*)(&sA[(nt*16 + l15)*256 + ((ks*64 + l4*16) ^ swz)]);
      acc[0][nt] = MFMA16(w0, x, acc[0][nt]);
      acc[1][nt] = MFMA16(w1, x, acc[1][nt]);
    }
  }
  // epilogue 3: +b3, mask, sum over 48 edges, /30, +h_V -> hOut (fp32)
#pragma unroll
  for (int m = 0; m < 2; ++m){
    int och0 = (wv*2 + m)*16 + l4*4;
    float q0 = b3[och0], q1 = b3[och0+1], q2 = b3[och0+2], q3 = b3[och0+3];
    float s0 = 0.f, s1 = 0.f, s2 = 0.f, s3 = 0.f;
#pragma unroll
    for (int nt = 0; nt < 3; ++nt){
      float mk = sMask[nt*16 + l15];
      s0 += mk * (acc[m][nt][0] + q0);
      s1 += mk * (acc[m][nt][1] + q1);
      s2 += mk * (acc[m][nt][2] + q2);
      s3 += mk * (acc[m][nt][3] + q3);
    }
#pragma unroll
    for (int off = 1; off < 16; off <<= 1){
      s0 += __shfl_xor(s0, off, 16);
      s1 += __shfl_xor(s1, off, 16);
      s2 += __shfl_xor(s2, off, 16);
      s3 += __shfl_xor(s3, off, 16);
    }
    if (l15 == 0){
      const float4 hv = *(const float4*)(hV + (size_t)node*128 + och0);
      float4 o;
      o.x = hv.x + s0 * (1.0f/30.0f);
      o.y = hv.y + s1 * (1.0f/30.0f);
      o.z = hv.z + s2 * (1.0f/30.0f);
      o.w = hv.w + s3 * (1.0f/30.0f);
      *(float4*)(hOut + (size_t)node*128 + och0) = o;
    }
  }
}

// ---------------- FFN ----------------
__global__ __launch_bounds__(256, 2)
void k_ffn(const float* __restrict__ h, const float* __restrict__ maskV,
           const unsigned short* __restrict__ wt,
           const float* __restrict__ bin, const float* __restrict__ bout,
           float* __restrict__ out)
{
  __shared__ char sH[32*256];    // 32 nodes x 128 bf16 (swizzled)
  __shared__ char sF[32*1024];   // 32 nodes x 512 bf16 (swizzled)

  const int tid = threadIdx.x;
  const int wv  = tid >> 6;
  const int ln  = tid & 63;
  const int l15 = ln & 15;
  const int l4  = ln >> 4;
  const int swz = (l15 & 7) << 4;
  const unsigned short* WinT  = wt + 65536;    // [512][128]
  const unsigned short* WoutT = wt + 131072;   // [128][512]
  const int nb = blockIdx.x * 32;              // flat node base

#pragma unroll
  for (int it = 0; it < 2; ++it){
    int cid = tid + it*256;          // 512 chunks: 32 rows x 16 chunks
    int r = cid >> 4, cb = cid & 15;
    const float* src = h + (size_t)(nb + r)*128 + cb*8;
    float4 a0 = *(const float4*)(src);
    float4 a1 = *(const float4*)(src + 4);
    uint4 w;
    w.x = pack2(a0.x, a0.y); w.y = pack2(a0.z, a0.w);
    w.z = pack2(a1.x, a1.y); w.w = pack2(a1.z, a1.w);
    *(uint4*)(&sH[r*256 + ((cb*16) ^ ((r&7)<<4))]) = w;
  }
  __syncthreads();

  // GEMM in: ff^T[512][32], K=128 — wave owns 8 f-tiles
  f32x4 accA[8][2];
#pragma unroll
  for (int m8 = 0; m8 < 8; ++m8){ accA[m8][0] = f32x4{0.f,0.f,0.f,0.f}; accA[m8][1] = f32x4{0.f,0.f,0.f,0.f}; }
#pragma unroll
  for (int ks = 0; ks < 4; ++ks){
    bf16x8 x0 = *(const bf16x8*)(&sH[(l15)*256      + ((ks*64 + l4*16) ^ swz)]);
    bf16x8 x1 = *(const bf16x8*)(&sH[(16 + l15)*256 + ((ks*64 + l4*16) ^ swz)]);
#pragma unroll
    for (int m8 = 0; m8 < 8; ++m8){
      int fr = (wv*8 + m8)*16 + l15;
      bf16x8 wf = *(const bf16x8*)(WinT + fr*128 + ks*32 + l4*8);
      accA[m8][0] = MFMA16(wf, x0, accA[m8][0]);
      accA[m8][1] = MFMA16(wf, x1, accA[m8][1]);
    }
  }
#pragma unroll
  for (int m8 = 0; m8 < 8; ++m8){
    int f0 = (wv*8 + m8)*16 + l4*4;
    float q0 = bin[f0], q1 = bin[f0+1], q2 = bin[f0+2], q3 = bin[f0+3];
#pragma unroll
    for (int nt = 0; nt < 2; ++nt){
      int row = nt*16 + l15;
      float g0 = gelu_erf_f(accA[m8][nt][0] + q0);
      float g1 = gelu_erf_f(accA[m8][nt][1] + q1);
      float g2 = gelu_erf_f(accA[m8][nt][2] + q2);
      float g3 = gelu_erf_f(accA[m8][nt][3] + q3);
      uint2 p; p.x = pack2(g0, g1); p.y = pack2(g2, g3);
      *(uint2*)(&sF[row*1024 + ((f0*2) ^ swz)]) = p;
    }
  }
  __syncthreads();

  // GEMM out: dh2^T[128][32], K=512 — wave owns 2 ch-tiles
  f32x4 accB[2][2];
#pragma unroll
  for (int m = 0; m < 2; ++m){ accB[m][0] = f32x4{0.f,0.f,0.f,0.f}; accB[m][1] = f32x4{0.f,0.f,0.f,0.f}; }
#pragma unroll
  for (int ks = 0; ks < 16; ++ks){
    bf16x8 x0 = *(const bf16x8*)(&sF[(l15)*1024      + ((ks*64 + l4*16) ^ swz)]);
    bf16x8 x1 = *(const bf16x8*)(&sF[(16 + l15)*1024 + ((ks*64 + l4*16) ^ swz)]);
#pragma unroll
    for (int m = 0; m < 2; ++m){
      int cr = (wv*2 + m)*16 + l15;
      bf16x8 wf = *(const bf16x8*)(WoutT + cr*512 + ks*32 + l4*8);
      accB[m][0] = MFMA16(wf, x0, accB[m][0]);
      accB[m][1] = MFMA16(wf, x1, accB[m][1]);
    }
  }
#pragma unroll
  for (int m = 0; m < 2; ++m){
    int ch0 = (wv*2 + m)*16 + l4*4;
    float q0 = bout[ch0], q1 = bout[ch0+1], q2 = bout[ch0+2], q3 = bout[ch0+3];
#pragma unroll
    for (int nt = 0; nt < 2; ++nt){
      int node = nb + nt*16 + l15;
      float mv = maskV[node];
      const float4 hv = *(const float4*)(h + (size_t)node*128 + ch0);
      float4 o;
      o.x = mv * (hv.x + accB[m][nt][0] + q0);
      o.y = mv * (hv.y + accB[m][nt][1] + q1);
      o.z = mv * (hv.z + accB[m][nt][2] + q2);
      o.w = mv * (hv.w + accB[m][nt][3] + q3);
      *(float4*)(out + (size_t)node*128 + ch0) = o;
    }
  }
}

extern "C" void kernel_launch(void* const* d_in, const int* in_sizes, int n_in,
                              void* d_out, int out_size, void* d_ws, size_t ws_size,
                              hipStream_t stream)
{
  const float* hV    = (const float*)d_in[0];
  const float* hE    = (const float*)d_in[1];
  const int*   Eidx  = (const int*)  d_in[2];
  const float* maskV = (const float*)d_in[3];
  const float* maskA = (const float*)d_in[4];
  const float* W1w = (const float*)d_in[5];
  const float* W1b = (const float*)d_in[6];
  const float* W2w = (const float*)d_in[7];
  const float* W2b = (const float*)d_in[8];
  const float* W3w = (const float*)d_in[9];
  const float* W3b = (const float*)d_in[10];
  const float* Winw  = (const float*)d_in[11];
  const float* Winb  = (const float*)d_in[12];
  const float* Woutw = (const float*)d_in[13];
  const float* Woutb = (const float*)d_in[14];
  float* out = (float*)d_out;

  unsigned short* wt = (unsigned short*)d_ws;                        // 384 KB bf16 weights
  float* hVp  = (float*)((char*)d_ws + (1u << 19));                  // 4 MB fp32 hVp @512KB
  float* hbuf = (float*)((char*)d_ws + (1u << 19) + (1u << 22));     // 4 MB fp32 h

  k_prep<<<dim3(768),  dim3(256), 0, stream>>>(W1w, W2w, W3w, Winw, Woutw, wt);
  k_hvp <<<dim3(256),  dim3(256), 0, stream>>>(hV, wt, W1b, hVp);
  k_msg <<<dim3(8192), dim3(256), 0, stream>>>(hV, hE, Eidx, maskA, wt, hVp, W2b, W3b, hbuf);
  k_ffn <<<dim3(256),  dim3(256), 0, stream>>>(hbuf, maskV, wt, Winb, Woutb, out);
}

// Round 3
// 152.846 us; speedup vs baseline: 1.3859x; 1.1125x over previous
//
#include <hip/hip_runtime.h>
#include <hip/hip_bf16.h>
#include <math.h>

typedef __attribute__((ext_vector_type(8))) short bf16x8;
typedef __attribute__((ext_vector_type(4))) float f32x4;

#define MFMA16(a,b,c) __builtin_amdgcn_mfma_f32_16x16x32_bf16((a),(b),(c),0,0,0)

__device__ __forceinline__ unsigned int pack2(float a, float b){
  __hip_bfloat162 h = __float22bfloat162_rn(float2{a, b});
  union { __hip_bfloat162 h; unsigned int u; } v; v.h = h;
  return v.u;
}
// gelu(tanh approx) = x * sigmoid(2*0.79788456*(x+0.044715x^3))
//                   = x * rcp(1 + exp2(-(c1*x + c3*x^3)))   (c's include log2e)
__device__ __forceinline__ float gelu_tanh_f(float x){
  float x2 = x * x;
  float z  = x * fmaf(x2, -0.10294823f, -2.3022082f);
  float e  = exp2f(z);
  return x * __builtin_amdgcn_rcpf(1.0f + e);
}
__device__ __forceinline__ float gelu_erf_f(float x){
  return 0.5f * x * (1.0f + erff(x * 0.70710678118654752f));
}

// ---------------- prep: weights -> bf16, [out][in] layout ----------------
// wt layout (elements): W1T[128][256] @0, W2T[128][128] @32768, W3T[128][128] @49152,
//                       WinT[512][128] @65536, WoutT[128][512] @131072  (total 196608)
__global__ void k_prep(const float* __restrict__ W1, const float* __restrict__ W2,
                       const float* __restrict__ W3, const float* __restrict__ Win,
                       const float* __restrict__ Wout, unsigned short* __restrict__ wt)
{
  int t = blockIdx.x * 256 + threadIdx.x;
  if (t >= 196608) return;
  float v;
  if (t < 32768){            int o = t >> 8,        i = t & 255;         v = W1[i*128 + o]; }
  else if (t < 49152){       int l = t - 32768, o = l >> 7, i = l & 127; v = W2[i*128 + o]; }
  else if (t < 65536){       int l = t - 49152, o = l >> 7, i = l & 127; v = W3[i*128 + o]; }
  else if (t < 131072){      int l = t - 65536, o = l >> 7, i = l & 127; v = Win[i*512 + o]; }
  else {                     int l = t - 131072, o = l >> 9, i = l & 511; v = Wout[i*128 + o]; }
  union { float f; unsigned int u; } w; w.f = v;
  unsigned int r = w.u + 0x7fffu + ((w.u >> 16) & 1u);
  wt[t] = (unsigned short)(r >> 16);
}

// ---------------- hVp = hV @ W1a^T + b1  (per node, fp32 out) ----------------
__global__ __launch_bounds__(256)
void k_hvp(const float* __restrict__ hV, const unsigned short* __restrict__ wt,
           const float* __restrict__ b1, float* __restrict__ hVp)
{
  __shared__ char sH[32*256];   // 32 nodes x 128 bf16 (swizzled)
  const int tid = threadIdx.x;
  const int wv  = tid >> 6;
  const int ln  = tid & 63;
  const int l15 = ln & 15;
  const int l4  = ln >> 4;
  const int swz = (l15 & 7) << 4;
  const unsigned short* W1T = wt;   // [128][256], cols 0..127 = h_V part
  const int nb = blockIdx.x * 32;

#pragma unroll
  for (int it = 0; it < 2; ++it){
    int cid = tid + it*256;       // 32 rows x 16 chunks
    int r = cid >> 4, cb = cid & 15;
    const float* src = hV + (size_t)(nb + r)*128 + cb*8;
    float4 a0 = *(const float4*)(src);
    float4 a1 = *(const float4*)(src + 4);
    uint4 w;
    w.x = pack2(a0.x, a0.y); w.y = pack2(a0.z, a0.w);
    w.z = pack2(a1.x, a1.y); w.w = pack2(a1.z, a1.w);
    *(uint4*)(&sH[r*256 + ((cb*16) ^ ((r&7)<<4))]) = w;
  }
  __syncthreads();

  f32x4 acc[2][2];
#pragma unroll
  for (int m = 0; m < 2; ++m){ acc[m][0] = f32x4{0.f,0.f,0.f,0.f}; acc[m][1] = f32x4{0.f,0.f,0.f,0.f}; }
#pragma unroll
  for (int ks = 0; ks < 4; ++ks){
    bf16x8 x0 = *(const bf16x8*)(&sH[(l15)*256      + ((ks*64 + l4*16) ^ swz)]);
    bf16x8 x1 = *(const bf16x8*)(&sH[(16 + l15)*256 + ((ks*64 + l4*16) ^ swz)]);
#pragma unroll
    for (int m = 0; m < 2; ++m){
      int orow = (wv*2 + m)*16 + l15;
      bf16x8 wf = *(const bf16x8*)(W1T + orow*256 + ks*32 + l4*8);
      acc[m][0] = MFMA16(wf, x0, acc[m][0]);
      acc[m][1] = MFMA16(wf, x1, acc[m][1]);
    }
  }
#pragma unroll
  for (int m = 0; m < 2; ++m){
    int och0 = (wv*2 + m)*16 + l4*4;
    float q0 = b1[och0], q1 = b1[och0+1], q2 = b1[och0+2], q3 = b1[och0+3];
#pragma unroll
    for (int nt = 0; nt < 2; ++nt){
      int node = nb + nt*16 + l15;
      float4 o;
      o.x = acc[m][nt][0] + q0;
      o.y = acc[m][nt][1] + q1;
      o.z = acc[m][nt][2] + q2;
      o.w = acc[m][nt][3] + q3;
      *(float4*)(hVp + (size_t)node*128 + och0) = o;
    }
  }
}

// ---------------- message MLP + aggregation: persistent, pipelined ----------------
// 512 threads (8 waves), each wave owns one 16-row output m-tile. 16 nodes/block.
#define NPB 16
__global__ __launch_bounds__(512, 4)
void k_msg(const float* __restrict__ hV, const float* __restrict__ hE,
           const int* __restrict__ Eidx, const float* __restrict__ maskA,
           const unsigned short* __restrict__ wt, const float* __restrict__ hVp,
           const float* __restrict__ b2, const float* __restrict__ b3,
           float* __restrict__ hOut)
{
  __shared__ char  sEV[2][12288];  // h_E tile (48x128 bf16, swizzled), double-buffered; cur also reused for m2
  __shared__ char  sM[12288];      // m1
  __shared__ int   sIdx[48];
  __shared__ float sMask[48];

  const int tid = threadIdx.x;
  const int wv  = tid >> 6;        // 0..7 -> m-tile
  const int ln  = tid & 63;
  const int l15 = ln & 15;
  const int l4  = ln >> 4;
  const int swz = (l15 & 7) << 4;

  const unsigned short* W1T = wt;            // [128][256]; h_E part at col 128
  const unsigned short* W2T = wt + 32768;    // [128][128]
  const unsigned short* W3T = wt + 49152;    // [128][128]

  // loop-invariant weight fragments (48 VGPR)
  bf16x8 w1f[4], w2f[4], w3f[4];
  {
    int orow = wv*16 + l15;
#pragma unroll
    for (int ks = 0; ks < 4; ++ks){
      w1f[ks] = *(const bf16x8*)(W1T + orow*256 + 128 + ks*32 + l4*8);
      w2f[ks] = *(const bf16x8*)(W2T + orow*128 + ks*32 + l4*8);
      w3f[ks] = *(const bf16x8*)(W3T + orow*128 + ks*32 + l4*8);
    }
  }
  const int och0 = wv*16 + l4*4;
  const float4 b2q = *(const float4*)(b2 + och0);
  const float4 b3q = *(const float4*)(b3 + och0);

  const int node0 = blockIdx.x * NPB;

  // prologue prefetch (node0): h_E tile as 1536 float4s; idx/mask
  float4 e0, e1, e2; int pIdx = 0; float pMask = 0.f;
  {
    const float4* ef = (const float4*)(hE + (size_t)node0 * 6144);
    e0 = ef[tid]; e1 = ef[tid + 512]; e2 = ef[tid + 1024];
    if (tid < 48){ pIdx = Eidx[node0*48 + tid]; pMask = maskA[node0*48 + tid]; }
  }

  for (int i = 0; i < NPB; ++i){
    const int node = node0 + i;
    const int b    = node >> 11;
    char* sE = sEV[i & 1];

    __syncthreads();   // protect sIdx/sMask (E1/E3 readers of prev node)

    // S1: convert + write staged h_E, idx/mask
    {
      int f0 = tid, f1 = tid + 512, f2 = tid + 1024;
      uint2 p;
      p.x = pack2(e0.x, e0.y); p.y = pack2(e0.z, e0.w);
      *(uint2*)(&sE[(f0>>5)*256 + (((f0&31)*8) ^ (((f0>>5)&7)<<4))]) = p;
      p.x = pack2(e1.x, e1.y); p.y = pack2(e1.z, e1.w);
      *(uint2*)(&sE[(f1>>5)*256 + (((f1&31)*8) ^ (((f1>>5)&7)<<4))]) = p;
      p.x = pack2(e2.x, e2.y); p.y = pack2(e2.z, e2.w);
      *(uint2*)(&sE[(f2>>5)*256 + (((f2&31)*8) ^ (((f2>>5)&7)<<4))]) = p;
      if (tid < 48){ sIdx[tid] = pIdx; sMask[tid] = pMask; }
    }
    // issue next node's prefetch now (latency hides under this whole iteration)
    if (i + 1 < NPB){
      const float4* ef = (const float4*)(hE + (size_t)(node + 1) * 6144);
      e0 = ef[tid]; e1 = ef[tid + 512]; e2 = ef[tid + 1024];
      if (tid < 48){ pIdx = Eidx[(node+1)*48 + tid]; pMask = maskA[(node+1)*48 + tid]; }
    }
    __syncthreads();

    // issue hVp gathers early (consumed after GEMM1)
    float4 hp0, hp1, hp2;
    {
      const float* base = hVp + (size_t)b*2048*128 + och0;
      hp0 = *(const float4*)(base + (size_t)sIdx[l15]      * 128);
      hp1 = *(const float4*)(base + (size_t)sIdx[16 + l15] * 128);
      hp2 = *(const float4*)(base + (size_t)sIdx[32 + l15] * 128);
    }

    f32x4 acc[3];
    // ---- GEMM1: K=128 (h_E x W1e)
#pragma unroll
    for (int nt = 0; nt < 3; ++nt) acc[nt] = f32x4{0.f,0.f,0.f,0.f};
#pragma unroll
    for (int ks = 0; ks < 4; ++ks){
#pragma unroll
      for (int nt = 0; nt < 3; ++nt){
        bf16x8 x = *(const bf16x8*)(&sE[(nt*16 + l15)*256 + ((ks*64 + l4*16) ^ swz)]);
        acc[nt] = MFMA16(w1f[ks], x, acc[nt]);
      }
    }
    // E1: + gathered hVp (has b1), gelu -> sM
#pragma unroll
    for (int nt = 0; nt < 3; ++nt){
      const float4 hp = (nt == 0) ? hp0 : (nt == 1) ? hp1 : hp2;
      int row = nt*16 + l15;
      float g0 = gelu_tanh_f(acc[nt][0] + hp.x);
      float g1 = gelu_tanh_f(acc[nt][1] + hp.y);
      float g2 = gelu_tanh_f(acc[nt][2] + hp.z);
      float g3 = gelu_tanh_f(acc[nt][3] + hp.w);
      uint2 p; p.x = pack2(g0, g1); p.y = pack2(g2, g3);
      *(uint2*)(&sM[row*256 + ((och0*2) ^ ((row&7)<<4))]) = p;
    }
    __syncthreads();

    // ---- GEMM2: K=128
#pragma unroll
    for (int nt = 0; nt < 3; ++nt) acc[nt] = f32x4{0.f,0.f,0.f,0.f};
#pragma unroll
    for (int ks = 0; ks < 4; ++ks){
#pragma unroll
      for (int nt = 0; nt < 3; ++nt){
        bf16x8 x = *(const bf16x8*)(&sM[(nt*16 + l15)*256 + ((ks*64 + l4*16) ^ swz)]);
        acc[nt] = MFMA16(w2f[ks], x, acc[nt]);
      }
    }
    // E2: bias + gelu -> sE (h_E consumed; all waves past prior barrier)
#pragma unroll
    for (int nt = 0; nt < 3; ++nt){
      int row = nt*16 + l15;
      float g0 = gelu_tanh_f(acc[nt][0] + b2q.x);
      float g1 = gelu_tanh_f(acc[nt][1] + b2q.y);
      float g2 = gelu_tanh_f(acc[nt][2] + b2q.z);
      float g3 = gelu_tanh_f(acc[nt][3] + b2q.w);
      uint2 p; p.x = pack2(g0, g1); p.y = pack2(g2, g3);
      *(uint2*)(&sE[row*256 + ((och0*2) ^ ((row&7)<<4))]) = p;
    }
    __syncthreads();

    // ---- GEMM3: K=128
#pragma unroll
    for (int nt = 0; nt < 3; ++nt) acc[nt] = f32x4{0.f,0.f,0.f,0.f};
#pragma unroll
    for (int ks = 0; ks < 4; ++ks){
#pragma unroll
      for (int nt = 0; nt < 3; ++nt){
        bf16x8 x = *(const bf16x8*)(&sE[(nt*16 + l15)*256 + ((ks*64 + l4*16) ^ swz)]);
        acc[nt] = MFMA16(w3f[ks], x, acc[nt]);
      }
    }
    // E3: +b3, mask, sum over 48 edges, /30, +h_V -> hOut
    {
      float s0 = 0.f, s1 = 0.f, s2 = 0.f, s3 = 0.f;
#pragma unroll
      for (int nt = 0; nt < 3; ++nt){
        float mk = sMask[nt*16 + l15];
        s0 += mk * (acc[nt][0] + b3q.x);
        s1 += mk * (acc[nt][1] + b3q.y);
        s2 += mk * (acc[nt][2] + b3q.z);
        s3 += mk * (acc[nt][3] + b3q.w);
      }
#pragma unroll
      for (int off = 1; off < 16; off <<= 1){
        s0 += __shfl_xor(s0, off, 16);
        s1 += __shfl_xor(s1, off, 16);
        s2 += __shfl_xor(s2, off, 16);
        s3 += __shfl_xor(s3, off, 16);
      }
      if (l15 == 0){
        const float4 hv = *(const float4*)(hV + (size_t)node*128 + och0);
        float4 o;
        o.x = hv.x + s0 * (1.0f/30.0f);
        o.y = hv.y + s1 * (1.0f/30.0f);
        o.z = hv.z + s2 * (1.0f/30.0f);
        o.w = hv.w + s3 * (1.0f/30.0f);
        *(float4*)(hOut + (size_t)node*128 + och0) = o;
      }
    }
  }
}

// ---------------- FFN ----------------
__global__ __launch_bounds__(256, 2)
void k_ffn(const float* __restrict__ h, const float* __restrict__ maskV,
           const unsigned short* __restrict__ wt,
           const float* __restrict__ bin, const float* __restrict__ bout,
           float* __restrict__ out)
{
  __shared__ char sH[32*256];    // 32 nodes x 128 bf16 (swizzled)
  __shared__ char sF[32*1024];   // 32 nodes x 512 bf16 (swizzled)

  const int tid = threadIdx.x;
  const int wv  = tid >> 6;
  const int ln  = tid & 63;
  const int l15 = ln & 15;
  const int l4  = ln >> 4;
  const int swz = (l15 & 7) << 4;
  const unsigned short* WinT  = wt + 65536;    // [512][128]
  const unsigned short* WoutT = wt + 131072;   // [128][512]
  const int nb = blockIdx.x * 32;              // flat node base

#pragma unroll
  for (int it = 0; it < 2; ++it){
    int cid = tid + it*256;          // 512 chunks: 32 rows x 16 chunks
    int r = cid >> 4, cb = cid & 15;
    const float* src = h + (size_t)(nb + r)*128 + cb*8;
    float4 a0 = *(const float4*)(src);
    float4 a1 = *(const float4*)(src + 4);
    uint4 w;
    w.x = pack2(a0.x, a0.y); w.y = pack2(a0.z, a0.w);
    w.z = pack2(a1.x, a1.y); w.w = pack2(a1.z, a1.w);
    *(uint4*)(&sH[r*256 + ((cb*16) ^ ((r&7)<<4))]) = w;
  }
  __syncthreads();

  // GEMM in: ff^T[512][32], K=128 — wave owns 8 f-tiles
  f32x4 accA[8][2];
#pragma unroll
  for (int m8 = 0; m8 < 8; ++m8){ accA[m8][0] = f32x4{0.f,0.f,0.f,0.f}; accA[m8][1] = f32x4{0.f,0.f,0.f,0.f}; }
#pragma unroll
  for (int ks = 0; ks < 4; ++ks){
    bf16x8 x0 = *(const bf16x8*)(&sH[(l15)*256      + ((ks*64 + l4*16) ^ swz)]);
    bf16x8 x1 = *(const bf16x8*)(&sH[(16 + l15)*256 + ((ks*64 + l4*16) ^ swz)]);
#pragma unroll
    for (int m8 = 0; m8 < 8; ++m8){
      int fr = (wv*8 + m8)*16 + l15;
      bf16x8 wf = *(const bf16x8*)(WinT + fr*128 + ks*32 + l4*8);
      accA[m8][0] = MFMA16(wf, x0, accA[m8][0]);
      accA[m8][1] = MFMA16(wf, x1, accA[m8][1]);
    }
  }
#pragma unroll
  for (int m8 = 0; m8 < 8; ++m8){
    int f0 = (wv*8 + m8)*16 + l4*4;
    float q0 = bin[f0], q1 = bin[f0+1], q2 = bin[f0+2], q3 = bin[f0+3];
#pragma unroll
    for (int nt = 0; nt < 2; ++nt){
      int row = nt*16 + l15;
      float g0 = gelu_erf_f(accA[m8][nt][0] + q0);
      float g1 = gelu_erf_f(accA[m8][nt][1] + q1);
      float g2 = gelu_erf_f(accA[m8][nt][2] + q2);
      float g3 = gelu_erf_f(accA[m8][nt][3] + q3);
      uint2 p; p.x = pack2(g0, g1); p.y = pack2(g2, g3);
      *(uint2*)(&sF[row*1024 + ((f0*2) ^ swz)]) = p;
    }
  }
  __syncthreads();

  // GEMM out: dh2^T[128][32], K=512 — wave owns 2 ch-tiles
  f32x4 accB[2][2];
#pragma unroll
  for (int m = 0; m < 2; ++m){ accB[m][0] = f32x4{0.f,0.f,0.f,0.f}; accB[m][1] = f32x4{0.f,0.f,0.f,0.f}; }
#pragma unroll
  for (int ks = 0; ks < 16; ++ks){
    bf16x8 x0 = *(const bf16x8*)(&sF[(l15)*1024      + ((ks*64 + l4*16) ^ swz)]);
    bf16x8 x1 = *(const bf16x8*)(&sF[(16 + l15)*1024 + ((ks*64 + l4*16) ^ swz)]);
#pragma unroll
    for (int m = 0; m < 2; ++m){
      int cr = (wv*2 + m)*16 + l15;
      bf16x8 wf = *(const bf16x8*)(WoutT + cr*512 + ks*32 + l4*8);
      accB[m][0] = MFMA16(wf, x0, accB[m][0]);
      accB[m][1] = MFMA16(wf, x1, accB[m][1]);
    }
  }
#pragma unroll
  for (int m = 0; m < 2; ++m){
    int ch0 = (wv*2 + m)*16 + l4*4;
    float q0 = bout[ch0], q1 = bout[ch0+1], q2 = bout[ch0+2], q3 = bout[ch0+3];
#pragma unroll
    for (int nt = 0; nt < 2; ++nt){
      int node = nb + nt*16 + l15;
      float mv = maskV[node];
      const float4 hv = *(const float4*)(h + (size_t)node*128 + ch0);
      float4 o;
      o.x = mv * (hv.x + accB[m][nt][0] + q0);
      o.y = mv * (hv.y + accB[m][nt][1] + q1);
      o.z = mv * (hv.z + accB[m][nt][2] + q2);
      o.w = mv * (hv.w + accB[m][nt][3] + q3);
      *(float4*)(out + (size_t)node*128 + ch0) = o;
    }
  }
}

extern "C" void kernel_launch(void* const* d_in, const int* in_sizes, int n_in,
                              void* d_out, int out_size, void* d_ws, size_t ws_size,
                              hipStream_t stream)
{
  const float* hV    = (const float*)d_in[0];
  const float* hE    = (const float*)d_in[1];
  const int*   Eidx  = (const int*)  d_in[2];
  const float* maskV = (const float*)d_in[3];
  const float* maskA = (const float*)d_in[4];
  const float* W1w = (const float*)d_in[5];
  const float* W1b = (const float*)d_in[6];
  const float* W2w = (const float*)d_in[7];
  const float* W2b = (const float*)d_in[8];
  const float* W3w = (const float*)d_in[9];
  const float* W3b = (const float*)d_in[10];
  const float* Winw  = (const float*)d_in[11];
  const float* Winb  = (const float*)d_in[12];
  const float* Woutw = (const float*)d_in[13];
  const float* Woutb = (const float*)d_in[14];
  float* out = (float*)d_out;

  unsigned short* wt = (unsigned short*)d_ws;                        // 384 KB bf16 weights
  float* hVp  = (float*)((char*)d_ws + (1u << 19));                  // 4 MB fp32 hVp @512KB
  float* hbuf = (float*)((char*)d_ws + (1u << 19) + (1u << 22));     // 4 MB fp32 h

  k_prep<<<dim3(768), dim3(256), 0, stream>>>(W1w, W2w, W3w, Winw, Woutw, wt);
  k_hvp <<<dim3(256), dim3(256), 0, stream>>>(hV, wt, W1b, hVp);
  k_msg <<<dim3(512), dim3(512), 0, stream>>>(hV, hE, Eidx, maskA, wt, hVp, W2b, W3b, hbuf);
  k_ffn <<<dim3(256), dim3(256), 0, stream>>>(hbuf, maskV, wt, Winb, Woutb, out);
}